// Round 5
// baseline (259.516 us; speedup 1.0000x reference)
//
#include <hip/hip_runtime.h>

typedef __attribute__((ext_vector_type(8))) short short8;
typedef __attribute__((ext_vector_type(4))) float floatx4;

__device__ __forceinline__ unsigned short f2b(float f) {
    union { float f; unsigned int i; } v; v.f = f;
    unsigned int u = v.i;
    u += 0x7FFFu + ((u >> 16) & 1u);   // round-nearest-even; NaN impossible here
    return (unsigned short)(u >> 16);
}

#define NTILES 2048   // 262144 rows / 128 rows-per-tile
#define GRID   1024   // every block does exactly 2 tiles: bid and bid+1024

// Block: 4 waves x 32 rows = 128 rows per tile.
// A = W (LDS), B = X  =>  C: col = x-row (lane-local), row = dout = n*16+q*4+r.
// R5 changes (evidence: R4 85us @ 3.0TB/s, traffic near-ideal, MfmaUtil 3.7,
// VALU 15, Occ 20 -> latency-bound; loadx dep-chain limits ~3 outstanding
// loads/wave vs ~9KB/CU needed by Little's law):
//  - loadx batches 8 dwordx4 loads into an array BEFORE packing (MLP ~8-12)
//  - X loads no longer nontemporal (bench re-runs dispatch; let X live in L3)
//  - VGPR must stay <=128 (occupancy class boundary; >128 halves waves/CU)
__global__ __launch_bounds__(256, 3) void mobius_linear_kernel(
    const float* __restrict__ X,
    const float* __restrict__ W,
    const float* __restrict__ Bias,
    float* __restrict__ Out)
{
    __shared__ unsigned short ldsW[128 * 136];
    __shared__ float ldsB[128];

    const int tid  = threadIdx.x;
    const int wave = tid >> 6;
    const int lane = tid & 63;
    const int q = lane >> 4;     // quad
    const int c = lane & 15;     // lane-local: x-row (B/C col) & W-row (A row)

    // ---- load + pack one X tile: 8 loads in flight per row-group, then pack ----
    auto loadx = [&](int T, short8 (&xf)[2][4], float (&xn)[2]) {
        const int rb = T * 128 + wave * 32;
        xn[0] = 0.f; xn[1] = 0.f;
#pragma unroll
        for (int g = 0; g < 2; ++g) {
            const float* xrow = X + (size_t)(rb + g * 16 + c) * 128;
            floatx4 xd[8];
#pragma unroll
            for (int kc = 0; kc < 4; ++kc) {
                xd[2 * kc]     = *reinterpret_cast<const floatx4*>(xrow + kc * 32 + q * 8);
                xd[2 * kc + 1] = *reinterpret_cast<const floatx4*>(xrow + kc * 32 + q * 8 + 4);
            }
#pragma unroll
            for (int kc = 0; kc < 4; ++kc) {
                short8 pk;
#pragma unroll
                for (int j = 0; j < 4; ++j) {
                    float a = xd[2 * kc][j], b = xd[2 * kc + 1][j];
                    xn[g] = fmaf(a, a, xn[g]);
                    xn[g] = fmaf(b, b, xn[g]);
                    pk[j] = (short)f2b(a); pk[4 + j] = (short)f2b(b);
                }
                xf[g][kc] = pk;
            }
        }
        // quads hold disjoint k-ranges of the same row; sum over q
        xn[0] += __shfl_xor(xn[0], 16); xn[0] += __shfl_xor(xn[0], 32);
        xn[1] += __shfl_xor(xn[1], 16); xn[1] += __shfl_xor(xn[1], 32);
    };

    // ---- stage W into LDS as bf16 (row stride 136 shorts = 272 B) ----
    auto stage_w = [&]() {
#pragma unroll
        for (int i = 0; i < 8; ++i) {
            int chunk = i * 256 + tid;          // 0..2047
            int row = chunk >> 4, cc = chunk & 15;
            const float* src = W + row * 128 + cc * 8;
            floatx4 w0 = *reinterpret_cast<const floatx4*>(src);
            floatx4 w1 = *reinterpret_cast<const floatx4*>(src + 4);
            short8 pk;
#pragma unroll
            for (int j = 0; j < 4; ++j) { pk[j] = (short)f2b(w0[j]); pk[4 + j] = (short)f2b(w1[j]); }
            *reinterpret_cast<short8*>(&ldsW[row * 136 + cc * 8]) = pk;
        }
    };

    short8 xfA[2][4], xfB[2][4];
    float xnA[2], xnB[2];
    const int t0 = blockIdx.x;
    const int t1 = blockIdx.x + GRID;

    // stagger: half the blocks stream X before touching W, so their W reads
    // arrive after the other half's L2 fills -> fewer HBM W misses
    if (blockIdx.x & 1) { loadx(t0, xfA, xnA); stage_w(); }
    else                { stage_w(); loadx(t0, xfA, xnA); }

    if (tid < 32)
        *reinterpret_cast<floatx4*>(&ldsB[tid * 4]) =
            *reinterpret_cast<const floatx4*>(Bias + tid * 4);

    __syncthreads();   // the ONLY barrier: LDS read-only from here on

    // ---- ||b||^2 ----
    float b2 = 0.f;
#pragma unroll
    for (int n = 0; n < 8; ++n) {
        floatx4 bv = *reinterpret_cast<const floatx4*>(&ldsB[n * 16 + q * 4]);
#pragma unroll
        for (int r = 0; r < 4; ++r) b2 = fmaf(bv[r], bv[r], b2);
    }
    b2 += __shfl_xor(b2, 16); b2 += __shfl_xor(b2, 32);

    floatx4 acc[2][8];

    auto mfma_all = [&](short8 (&xf)[2][4]) {
#pragma unroll
        for (int g = 0; g < 2; ++g)
#pragma unroll
            for (int n = 0; n < 8; ++n)
                acc[g][n] = (floatx4){0.f, 0.f, 0.f, 0.f};
#pragma unroll
        for (int kc = 0; kc < 4; ++kc) {
#pragma unroll
            for (int n = 0; n < 8; ++n) {
                short8 wf = *reinterpret_cast<const short8*>(
                    &ldsW[(n * 16 + c) * 136 + kc * 32 + q * 8]);
                acc[0][n] = __builtin_amdgcn_mfma_f32_16x16x32_bf16(wf, xf[0][kc], acc[0][n], 0, 0, 0);
                acc[1][n] = __builtin_amdgcn_mfma_f32_16x16x32_bf16(wf, xf[1][kc], acc[1][n], 0, 0, 0);
            }
        }
    };

    // lane owns x-row (rb + g*16 + c), douts {n*16 + q*4 + r}
    auto epilogue = [&](int T, float (&xn)[2]) {
        const int rb = T * 128 + wave * 32;
        floatx4 bfr[8];
#pragma unroll
        for (int n = 0; n < 8; ++n)
            bfr[n] = *reinterpret_cast<const floatx4*>(&ldsB[n * 16 + q * 4]);
#pragma unroll
        for (int g = 0; g < 2; ++g) {
            float m2 = 0.f, mbv = 0.f;
#pragma unroll
            for (int n = 0; n < 8; ++n)
#pragma unroll
                for (int r = 0; r < 4; ++r) {
                    float v = acc[g][n][r];
                    m2  = fmaf(v, v, m2);
                    mbv = fmaf(v, bfr[n][r], mbv);
                }
            // disjoint dout-sets across quads; sum over q
            m2  += __shfl_xor(m2, 16);  m2  += __shfl_xor(m2, 32);
            mbv += __shfl_xor(mbv, 16); mbv += __shfl_xor(mbv, 32);

            float xnorm = fmaxf(sqrtf(xn[g]), 1e-15f);
            float u     = fminf(xnorm, 1.f - 1e-7f);
            float at    = 0.5f * __logf((1.f + u) / (1.f - u));   // artanh
            float Mxn   = fmaxf(sqrtf(m2), 1e-15f);
            float arg   = Mxn / xnorm * at;                        // >= 0
            float e     = __expf(2.f * arg);
            float th    = 1.f - 2.f / (e + 1.f);                   // tanh
            float scale = (Mxn <= 1e-10f) ? 0.f : th / Mxn;
            float y2 = scale * scale * m2;                         // ||y||^2
            float yb = scale * mbv;                                // y.b
            float t1v = 1.f + 2.f * yb + b2;
            float den = fmaxf(fmaf(y2, b2, 1.f + 2.f * yb), 1e-15f);
            float Af = t1v * scale / den;        // z = Af*Mx + Bf*bias
            float Bf = (1.f - y2) / den;
            float zn2 = Af * Af * m2 + 2.f * Af * Bf * mbv + Bf * Bf * b2;
            float zn  = fmaxf(sqrtf(zn2), 1e-15f);
            const float maxn = 1.f - 1e-5f;
            float fac = (zn > maxn) ? (maxn / zn) : 1.f;
            Af *= fac; Bf *= fac;

            float* orow = Out + (size_t)(rb + g * 16 + c) * 128;
#pragma unroll
            for (int n = 0; n < 8; ++n) {
                floatx4 o;
#pragma unroll
                for (int r = 0; r < 4; ++r)
                    o[r] = fmaf(Af, acc[g][n][r], Bf * bfr[n][r]);
                *reinterpret_cast<floatx4*>(orow + n * 16 + q * 4) = o;   // plain store
            }
        }
    };

    // ---- straight-line 2-tile pipeline ----
    mfma_all(xfA);
    loadx(t1, xfB, xnB);       // in-flight while epilogue(A) runs
    epilogue(t0, xnA);
    mfma_all(xfB);
    epilogue(t1, xnB);
}

extern "C" void kernel_launch(void* const* d_in, const int* in_sizes, int n_in,
                              void* d_out, int out_size, void* d_ws, size_t ws_size,
                              hipStream_t stream) {
    const float* X    = (const float*)d_in[0];
    const float* W    = (const float*)d_in[1];
    const float* Bias = (const float*)d_in[2];
    float* Out = (float*)d_out;

    dim3 grid(GRID), block(256);
    hipLaunchKernelGGL(mobius_linear_kernel, grid, block, 0, stream, X, W, Bias, Out);
}

// Round 6
// 259.492 us; speedup vs baseline: 1.0001x; 1.0001x over previous
//
#include <hip/hip_runtime.h>

typedef __attribute__((ext_vector_type(8))) short short8;
typedef __attribute__((ext_vector_type(4))) float floatx4;

__device__ __forceinline__ unsigned short f2b(float f) {
    union { float f; unsigned int i; } v; v.f = f;
    unsigned int u = v.i;
    u += 0x7FFFu + ((u >> 16) & 1u);   // round-nearest-even; NaN impossible here
    return (unsigned short)(u >> 16);
}

#define NTILES 2048   // 262144 rows / 128 rows-per-tile
#define GRID   1024   // every block does exactly 2 tiles: bid and bid+1024

// Block: 4 waves x 32 rows = 128 rows per tile.
// A = W (LDS), B = X  =>  C: col = x-row (lane-local), row = dout = n*16+q*4+r.
// R6 (evidence: R4 85us/3.0TB/s latency-bound, R5 confounded A/B regressed):
//  - revert to R4 state (nt X loads, interleaved first-tile pack, plain stores)
//  - T14-style cross-phase prefetch: issue tile-B g0 loads BEFORE mfma(A)
//    (latency hides under ~640cy of MFMA), pack g0, issue g1 loads BEFORE
//    epilogue(A) (hides under transcendental chain + stores), pack g1.
//  - VGPR peak est ~160 < 170 cap of (256,3); spill signature = FETCH/WRITE up.
__global__ __launch_bounds__(256, 3) void mobius_linear_kernel(
    const float* __restrict__ X,
    const float* __restrict__ W,
    const float* __restrict__ Bias,
    float* __restrict__ Out)
{
    __shared__ unsigned short ldsW[128 * 136];
    __shared__ float ldsB[128];

    const int tid  = threadIdx.x;
    const int wave = tid >> 6;
    const int lane = tid & 63;
    const int q = lane >> 4;     // quad
    const int c = lane & 15;     // lane-local: x-row (B/C col) & W-row (A row)

    // ---- R4-style load+pack (interleaved; used for tile A where there is
    //      no compute phase to hide under) ----
    auto loadx = [&](int T, short8 (&xf)[2][4], float (&xn)[2]) {
        const int rb = T * 128 + wave * 32;
        xn[0] = 0.f; xn[1] = 0.f;
#pragma unroll
        for (int g = 0; g < 2; ++g) {
            const float* xrow = X + (size_t)(rb + g * 16 + c) * 128;
#pragma unroll
            for (int kc = 0; kc < 4; ++kc) {
                const floatx4* src = reinterpret_cast<const floatx4*>(xrow + kc * 32 + q * 8);
                floatx4 x0 = __builtin_nontemporal_load(src);
                floatx4 x1 = __builtin_nontemporal_load(src + 1);
                short8 pk;
#pragma unroll
                for (int j = 0; j < 4; ++j) {
                    xn[g] = fmaf(x0[j], x0[j], xn[g]);
                    xn[g] = fmaf(x1[j], x1[j], xn[g]);
                    pk[j] = (short)f2b(x0[j]); pk[4 + j] = (short)f2b(x1[j]);
                }
                xf[g][kc] = pk;
            }
        }
        xn[0] += __shfl_xor(xn[0], 16); xn[0] += __shfl_xor(xn[0], 32);
        xn[1] += __shfl_xor(xn[1], 16); xn[1] += __shfl_xor(xn[1], 32);
    };

    // ---- split issue / pack for the pipelined tile B ----
    auto issue8 = [&](int T, int g, floatx4 (&xd)[8]) {
        const int rb = T * 128 + wave * 32;
        const float* xrow = X + (size_t)(rb + g * 16 + c) * 128;
#pragma unroll
        for (int kc = 0; kc < 4; ++kc) {
            const floatx4* src = reinterpret_cast<const floatx4*>(xrow + kc * 32 + q * 8);
            xd[2 * kc]     = __builtin_nontemporal_load(src);
            xd[2 * kc + 1] = __builtin_nontemporal_load(src + 1);
        }
    };
    auto pack8 = [&](floatx4 (&xd)[8], short8 (&xfg)[4], float& xn) {
        float s = 0.f;
#pragma unroll
        for (int kc = 0; kc < 4; ++kc) {
            short8 pk;
#pragma unroll
            for (int j = 0; j < 4; ++j) {
                float a = xd[2 * kc][j], b = xd[2 * kc + 1][j];
                s = fmaf(a, a, s);
                s = fmaf(b, b, s);
                pk[j] = (short)f2b(a); pk[4 + j] = (short)f2b(b);
            }
            xfg[kc] = pk;
        }
        s += __shfl_xor(s, 16); s += __shfl_xor(s, 32);
        xn = s;
    };

    // ---- stage W into LDS as bf16 (row stride 136 shorts = 272 B) ----
    auto stage_w = [&]() {
#pragma unroll
        for (int i = 0; i < 8; ++i) {
            int chunk = i * 256 + tid;          // 0..2047
            int row = chunk >> 4, cc = chunk & 15;
            const float* src = W + row * 128 + cc * 8;
            floatx4 w0 = *reinterpret_cast<const floatx4*>(src);
            floatx4 w1 = *reinterpret_cast<const floatx4*>(src + 4);
            short8 pk;
#pragma unroll
            for (int j = 0; j < 4; ++j) { pk[j] = (short)f2b(w0[j]); pk[4 + j] = (short)f2b(w1[j]); }
            *reinterpret_cast<short8*>(&ldsW[row * 136 + cc * 8]) = pk;
        }
    };

    short8 xfA[2][4], xfB[2][4];
    float xnA[2], xnB[2];
    const int t0 = blockIdx.x;
    const int t1 = blockIdx.x + GRID;

    // stagger: half the blocks stream X before touching W (breaks W miss-storm)
    if (blockIdx.x & 1) { loadx(t0, xfA, xnA); stage_w(); }
    else                { stage_w(); loadx(t0, xfA, xnA); }

    if (tid < 32)
        *reinterpret_cast<floatx4*>(&ldsB[tid * 4]) =
            *reinterpret_cast<const floatx4*>(Bias + tid * 4);

    __syncthreads();   // the ONLY barrier: LDS read-only from here on

    // ---- ||b||^2 ----
    float b2 = 0.f;
#pragma unroll
    for (int n = 0; n < 8; ++n) {
        floatx4 bv = *reinterpret_cast<const floatx4*>(&ldsB[n * 16 + q * 4]);
#pragma unroll
        for (int r = 0; r < 4; ++r) b2 = fmaf(bv[r], bv[r], b2);
    }
    b2 += __shfl_xor(b2, 16); b2 += __shfl_xor(b2, 32);

    floatx4 acc[2][8];

    auto mfma_all = [&](short8 (&xf)[2][4]) {
#pragma unroll
        for (int g = 0; g < 2; ++g)
#pragma unroll
            for (int n = 0; n < 8; ++n)
                acc[g][n] = (floatx4){0.f, 0.f, 0.f, 0.f};
#pragma unroll
        for (int kc = 0; kc < 4; ++kc) {
#pragma unroll
            for (int n = 0; n < 8; ++n) {
                short8 wf = *reinterpret_cast<const short8*>(
                    &ldsW[(n * 16 + c) * 136 + kc * 32 + q * 8]);
                acc[0][n] = __builtin_amdgcn_mfma_f32_16x16x32_bf16(wf, xf[0][kc], acc[0][n], 0, 0, 0);
                acc[1][n] = __builtin_amdgcn_mfma_f32_16x16x32_bf16(wf, xf[1][kc], acc[1][n], 0, 0, 0);
            }
        }
    };

    // lane owns x-row (rb + g*16 + c), douts {n*16 + q*4 + r}
    auto epilogue = [&](int T, float (&xn)[2]) {
        const int rb = T * 128 + wave * 32;
        floatx4 bfr[8];
#pragma unroll
        for (int n = 0; n < 8; ++n)
            bfr[n] = *reinterpret_cast<const floatx4*>(&ldsB[n * 16 + q * 4]);
#pragma unroll
        for (int g = 0; g < 2; ++g) {
            float m2 = 0.f, mbv = 0.f;
#pragma unroll
            for (int n = 0; n < 8; ++n)
#pragma unroll
                for (int r = 0; r < 4; ++r) {
                    float v = acc[g][n][r];
                    m2  = fmaf(v, v, m2);
                    mbv = fmaf(v, bfr[n][r], mbv);
                }
            m2  += __shfl_xor(m2, 16);  m2  += __shfl_xor(m2, 32);
            mbv += __shfl_xor(mbv, 16); mbv += __shfl_xor(mbv, 32);

            float xnorm = fmaxf(sqrtf(xn[g]), 1e-15f);
            float u     = fminf(xnorm, 1.f - 1e-7f);
            float at    = 0.5f * __logf((1.f + u) / (1.f - u));   // artanh
            float Mxn   = fmaxf(sqrtf(m2), 1e-15f);
            float arg   = Mxn / xnorm * at;                        // >= 0
            float e     = __expf(2.f * arg);
            float th    = 1.f - 2.f / (e + 1.f);                   // tanh
            float scale = (Mxn <= 1e-10f) ? 0.f : th / Mxn;
            float y2 = scale * scale * m2;                         // ||y||^2
            float yb = scale * mbv;                                // y.b
            float t1v = 1.f + 2.f * yb + b2;
            float den = fmaxf(fmaf(y2, b2, 1.f + 2.f * yb), 1e-15f);
            float Af = t1v * scale / den;        // z = Af*Mx + Bf*bias
            float Bf = (1.f - y2) / den;
            float zn2 = Af * Af * m2 + 2.f * Af * Bf * mbv + Bf * Bf * b2;
            float zn  = fmaxf(sqrtf(zn2), 1e-15f);
            const float maxn = 1.f - 1e-5f;
            float fac = (zn > maxn) ? (maxn / zn) : 1.f;
            Af *= fac; Bf *= fac;

            float* orow = Out + (size_t)(rb + g * 16 + c) * 128;
#pragma unroll
            for (int n = 0; n < 8; ++n) {
                floatx4 o;
#pragma unroll
                for (int r = 0; r < 4; ++r)
                    o[r] = fmaf(Af, acc[g][n][r], Bf * bfr[n][r]);
                *reinterpret_cast<floatx4*>(orow + n * 16 + q * 4) = o;   // plain store
            }
        }
    };

    // ---- pipelined 2-tile schedule ----
    floatx4 xd[8];
    issue8(t1, 0, xd);          // B.g0 latency hides under mfma(A)
    mfma_all(xfA);
    pack8(xd, xfB[0], xnB[0]);
    issue8(t1, 1, xd);          // B.g1 latency hides under epilogue(A)
    epilogue(t0, xnA);
    pack8(xd, xfB[1], xnB[1]);
    mfma_all(xfB);
    epilogue(t1, xnB);
}

extern "C" void kernel_launch(void* const* d_in, const int* in_sizes, int n_in,
                              void* d_out, int out_size, void* d_ws, size_t ws_size,
                              hipStream_t stream) {
    const float* X    = (const float*)d_in[0];
    const float* W    = (const float*)d_in[1];
    const float* Bias = (const float*)d_in[2];
    float* Out = (float*)d_out;

    dim3 grid(GRID), block(256);
    hipLaunchKernelGGL(mobius_linear_kernel, grid, block, 0, stream, X, W, Bias, Out);
}